// Round 6
// baseline (19245.107 us; speedup 1.0000x reference)
//
#include <hip/hip_runtime.h>

__device__ __forceinline__ float b2f(ushort u){
  union { float f; unsigned int i; } v; v.i = ((unsigned int)u) << 16; return v.f;
}
__device__ __forceinline__ ushort f2b(float f){
  union { float f; unsigned int i; } v; v.f = f;
  unsigned int r = (v.i + 0x7FFFu + ((v.i >> 16) & 1u)) >> 16;
  return (ushort)r;
}
// flag-typed load: f=1 -> fp32 array, f=0 -> bf16(ushort) array
__device__ __forceinline__ float ldf(const void* p, size_t i, int f){
  return f ? ((const float*)p)[i] : b2f(((const ushort*)p)[i]);
}

// ---------------------------------------------------------------------------
// Input storage detector on x: packed bf16 -> 0 ; fp32 (any) -> 1.
// ---------------------------------------------------------------------------
__global__ void detect_k(const void* __restrict__ x, int* __restrict__ flag)
{
  const int lane = threadIdx.x; // 64
  const ushort* p = (const ushort*)x;
  int wild = 0, zeven = 0;
#pragma unroll
  for (int j = 0; j < 8; ++j) {
    const int idx = lane * 8 + j;
    const ushort u = p[idx];
    if (((u >> 7) & 0xFF) >= 0xF1) ++wild;
    if (((idx & 1) == 0) && u == 0) ++zeven;
  }
#pragma unroll
  for (int off = 1; off < 64; off <<= 1) {
    wild += __shfl_xor(wild, off);
    zeven += __shfl_xor(zeven, off);
  }
  if (lane == 0) *flag = (wild >= 4 || zeven >= 128) ? 1 : 0;
}

// W table: logits = sq*sk * sum_d wt[d]*q_d*k_d  with 1/8 folded in.
// wt[d] = (F^2+G^2)/8, F=10000^(-i/16), G=10000^(-(2i+1)/32), i=(d>>1)&15.
__global__ void wtab_k(float* __restrict__ w, int* __restrict__ zeroc)
{
  const int d = threadIdx.x; // 64
  const int i = (d >> 1) & 15;
  const double F2 = pow(10000.0, -(double)i / 8.0);
  const double G2 = pow(10000.0, -(double)(2 * i + 1) / 16.0);
  w[d] = (float)((F2 + G2) * 0.125);
  if (d == 0) *zeroc = 0;
}

// ---------------------------------------------------------------------------
// Simple tiled GEMM: C[M][N] = A[M][K] @ W[K][N] + bias, fp32 accumulate.
// 64x64 tile, 256 threads, 4x4 outputs/thread, K-step 16. Operands flag-typed.
// MODE 0: q-scatter  -> outF[(h*2048+s)*64+d] = v*wtab[d]   (s=gr&2047)
// MODE 1: k-scatter  -> outF[(h*2048+s)*64+d] = v
// MODE 2: v-scatter  -> outU[(h*2048+s)*64+d] = bf16(v)
// MODE 3: relu       -> outU[gr*N+gc] = bf16(max(v,0))
// MODE 4: +res       -> outU[gr*1024+gc] = bf16(v + res)
// MODE 5: +res       -> outF[gr*1024+gc] = fp32(v + res)    (final, d_out)
// ---------------------------------------------------------------------------
template<int MODE>
__global__ __launch_bounds__(256) void sgemm(
    const void* __restrict__ A, const int* __restrict__ afp, int arow0,
    const void* __restrict__ W, const void* __restrict__ bias,
    const int* __restrict__ wfp,
    const void* __restrict__ res, const int* __restrict__ rfp,
    ushort* __restrict__ outU, float* __restrict__ outF,
    const float* __restrict__ wtab,
    int N, int K, int erow0)
{
  __shared__ float As[64][17];
  __shared__ float Ws[16][65];
  const int tid = threadIdx.x;
  const int tx = tid & 15, ty = tid >> 4;
  const int bn = blockIdx.x * 64, bm = blockIdx.y * 64;
  const int af = *afp, wf = *wfp;

  float acc[4][4] = {};

  for (int k0 = 0; k0 < K; k0 += 16) {
    __syncthreads();
#pragma unroll
    for (int u = 0; u < 4; ++u) {           // stage A: 64 rows x 16 k
      const int idx = tid * 4 + u;
      const int row = idx >> 4, kk = idx & 15;
      As[row][kk] = ldf(A, (size_t)(arow0 + bm + row) * K + k0 + kk, af);
    }
#pragma unroll
    for (int u = 0; u < 4; ++u) {           // stage W: 16 k x 64 cols
      const int idx = tid * 4 + u;
      const int kk = idx >> 6, col = idx & 63;
      Ws[kk][col] = ldf(W, (size_t)(k0 + kk) * N + bn + col, wf);
    }
    __syncthreads();
#pragma unroll
    for (int kk = 0; kk < 16; ++kk) {
      float ar[4], wr[4];
#pragma unroll
      for (int i = 0; i < 4; ++i) ar[i] = As[ty * 4 + i][kk];
#pragma unroll
      for (int j = 0; j < 4; ++j) wr[j] = Ws[kk][tx * 4 + j];
#pragma unroll
      for (int i = 0; i < 4; ++i)
#pragma unroll
        for (int j = 0; j < 4; ++j) acc[i][j] += ar[i] * wr[j];
    }
  }

  const int rf = (MODE >= 4) ? *rfp : 0;
#pragma unroll
  for (int i = 0; i < 4; ++i) {
    const int gr = erow0 + bm + ty * 4 + i;
#pragma unroll
    for (int j = 0; j < 4; ++j) {
      const int gc = bn + tx * 4 + j;
      float v = acc[i][j] + ldf(bias, gc, wf);
      if (MODE == 0) {
        const int hh = gc >> 6, dh = gc & 63, s = gr & 2047;
        outF[(((size_t)hh * 2048) + s) * 64 + dh] = v * wtab[dh];
      } else if (MODE == 1) {
        const int hh = gc >> 6, dh = gc & 63, s = gr & 2047;
        outF[(((size_t)hh * 2048) + s) * 64 + dh] = v;
      } else if (MODE == 2) {
        const int hh = gc >> 6, dh = gc & 63, s = gr & 2047;
        outU[(((size_t)hh * 2048) + s) * 64 + dh] = f2b(v);
      } else if (MODE == 3) {
        outU[(size_t)gr * N + gc] = f2b(fmaxf(v, 0.f));
      } else if (MODE == 4) {
        v += ldf(res, (size_t)gr * 1024 + gc, rf);
        outU[(size_t)gr * 1024 + gc] = f2b(v);
      } else {
        v += ldf(res, (size_t)gr * 1024 + gc, rf);
        outF[(size_t)gr * 1024 + gc] = v;
      }
    }
  }
}

// ---------------------------------------------------------------------------
// Attention pass 1: row max of logits. One thread per q-row.
// qb,kb: [16][2048][64] fp32 (one batch). grid (8, 16), block 256.
// L(s, c0+j) = sq*sk * dot64(q~, k)   (wtab & 1/8 already folded into q~)
// ---------------------------------------------------------------------------
__global__ __launch_bounds__(256) void attn_max_k(
    const float* __restrict__ qb, const float* __restrict__ kb,
    float* __restrict__ mrow)
{
  __shared__ float kS[64][64];
  const int tid = threadIdx.x;
  const int h = blockIdx.y;
  const int s = blockIdx.x * 256 + tid;

  float qv[64];
  const float4* qp = (const float4*)(qb + (((size_t)h * 2048) + s) * 64);
#pragma unroll
  for (int w = 0; w < 16; ++w) {
    const float4 t = qp[w];
    qv[w * 4] = t.x; qv[w * 4 + 1] = t.y; qv[w * 4 + 2] = t.z; qv[w * 4 + 3] = t.w;
  }
  const float sq = (float)s;
  float m = -3.0e38f;

  for (int c0 = 0; c0 < 2048; c0 += 64) {
    __syncthreads();
    {
      const int key = tid >> 2, seg = tid & 3;
      const float4* sp = (const float4*)(kb + (((size_t)h * 2048) + c0 + key) * 64 + seg * 16);
      float4* dp = (float4*)(&kS[key][seg * 16]);
#pragma unroll
      for (int u = 0; u < 4; ++u) dp[u] = sp[u];
    }
    __syncthreads();
    for (int j = 0; j < 64; ++j) {
      float a = 0.f;
#pragma unroll
      for (int d = 0; d < 64; ++d) a += qv[d] * kS[j][d];
      const float L = a * sq * (float)(c0 + j);
      m = fmaxf(m, L);
    }
  }
  mrow[h * 2048 + s] = m;
}

// ---------------------------------------------------------------------------
// Attention pass 2: softmax-accumulate with known row max (bit-identical L).
// vb: [16][2048][64] bf16. ctx out: [B][S][1024] bf16 (batch b).
// ---------------------------------------------------------------------------
__global__ __launch_bounds__(256) void attn_acc_k(
    const float* __restrict__ qb, const float* __restrict__ kb,
    const ushort* __restrict__ vb, const float* __restrict__ mrow,
    ushort* __restrict__ ctx, int b)
{
  __shared__ float kS[64][64];
  __shared__ float vS[64][64];
  const int tid = threadIdx.x;
  const int h = blockIdx.y;
  const int s = blockIdx.x * 256 + tid;

  float qv[64];
  const float4* qp = (const float4*)(qb + (((size_t)h * 2048) + s) * 64);
#pragma unroll
  for (int w = 0; w < 16; ++w) {
    const float4 t = qp[w];
    qv[w * 4] = t.x; qv[w * 4 + 1] = t.y; qv[w * 4 + 2] = t.z; qv[w * 4 + 3] = t.w;
  }
  const float sq = (float)s;
  const float m = mrow[h * 2048 + s];
  float l = 0.f;
  float o[64];
#pragma unroll
  for (int d = 0; d < 64; ++d) o[d] = 0.f;

  for (int c0 = 0; c0 < 2048; c0 += 64) {
    __syncthreads();
    {
      const int key = tid >> 2, seg = tid & 3;
      const float4* sp = (const float4*)(kb + (((size_t)h * 2048) + c0 + key) * 64 + seg * 16);
      float4* dp = (float4*)(&kS[key][seg * 16]);
#pragma unroll
      for (int u = 0; u < 4; ++u) dp[u] = sp[u];
      const ushort* vp = vb + (((size_t)h * 2048) + c0 + key) * 64 + seg * 16;
#pragma unroll
      for (int u = 0; u < 16; ++u) vS[key][seg * 16 + u] = b2f(vp[u]);
    }
    __syncthreads();
    for (int j = 0; j < 64; ++j) {
      float a = 0.f;
#pragma unroll
      for (int d = 0; d < 64; ++d) a += qv[d] * kS[j][d];
      const float L = a * sq * (float)(c0 + j);
      const float p = expf(L - m);
      l += p;
#pragma unroll
      for (int d = 0; d < 64; ++d) o[d] += p * vS[j][d];
    }
  }

  const float inv = 1.f / l;
  ushort* op = ctx + (((size_t)b * 2048) + s) * 1024 + h * 64;
#pragma unroll
  for (int d = 0; d < 64; ++d) op[d] = f2b(o[d] * inv);
}

// ---------------------------------------------------------------------------
// LayerNorm over 1024 cols, bf16 in -> bf16 out. One block per row.
// ---------------------------------------------------------------------------
__global__ __launch_bounds__(256) void ln_k(const ushort* __restrict__ y,
                                            const void* __restrict__ g,
                                            const void* __restrict__ be,
                                            const int* __restrict__ fp,
                                            ushort* __restrict__ out)
{
  const int row = blockIdx.x, tid = threadIdx.x;
  const int f = *fp;
  const ushort* p = y + (size_t)row * 1024;
  float v[4], s = 0.f, s2 = 0.f;
#pragma unroll
  for (int i = 0; i < 4; ++i) {
    const float x = b2f(p[tid + i * 256]);
    v[i] = x; s += x; s2 += x * x;
  }
#pragma unroll
  for (int off = 1; off < 64; off <<= 1) { s += __shfl_xor(s, off); s2 += __shfl_xor(s2, off); }
  __shared__ float red[8];
  const int wave = tid >> 6, lane = tid & 63;
  if (lane == 0) { red[wave] = s; red[4 + wave] = s2; }
  __syncthreads();
  s = red[0] + red[1] + red[2] + red[3];
  s2 = red[4] + red[5] + red[6] + red[7];
  const float mu = s * (1.f / 1024.f);
  const float var = s2 * (1.f / 1024.f) - mu * mu;
  const float rstd = rsqrtf(var + 1e-5f);
  ushort* o = out + (size_t)row * 1024;
#pragma unroll
  for (int i = 0; i < 4; ++i) {
    const int c = tid + i * 256;
    o[c] = f2b((v[i] - mu) * rstd * ldf(g, c, f) + ldf(be, c, f));
  }
}

// ---------------------------------------------------------------------------
// Final LayerNorm: fp32 in -> fp32 out, in place on d_out.
// ---------------------------------------------------------------------------
__global__ __launch_bounds__(256) void ln_f32_k(float* __restrict__ y,
                                                const void* __restrict__ g,
                                                const void* __restrict__ be,
                                                const int* __restrict__ fp)
{
  const int row = blockIdx.x, tid = threadIdx.x;
  const int f = *fp;
  float* p = y + (size_t)row * 1024;
  float v[4], s = 0.f, s2 = 0.f;
#pragma unroll
  for (int i = 0; i < 4; ++i) {
    const float x = p[tid + i * 256];
    v[i] = x; s += x; s2 += x * x;
  }
#pragma unroll
  for (int off = 1; off < 64; off <<= 1) { s += __shfl_xor(s, off); s2 += __shfl_xor(s2, off); }
  __shared__ float red[8];
  const int wave = tid >> 6, lane = tid & 63;
  if (lane == 0) { red[wave] = s; red[4 + wave] = s2; }
  __syncthreads();
  s = red[0] + red[1] + red[2] + red[3];
  s2 = red[4] + red[5] + red[6] + red[7];
  const float mu = s * (1.f / 1024.f);
  const float var = s2 * (1.f / 1024.f) - mu * mu;
  const float rstd = rsqrtf(var + 1e-5f);
#pragma unroll
  for (int i = 0; i < 4; ++i) {
    const int c = tid + i * 256;
    p[c] = (v[i] - mu) * rstd * ldf(g, c, f) + ldf(be, c, f);
  }
}

// ---------------------------------------------------------------------------
extern "C" void kernel_launch(void* const* d_in, const int* in_sizes, int n_in,
                              void* d_out, int out_size, void* d_ws, size_t ws_size,
                              hipStream_t stream)
{
  const void* x  = d_in[0];
  const void* wq = d_in[1];  const void* bq = d_in[2];
  const void* wk = d_in[3];  const void* bk = d_in[4];
  const void* wv = d_in[5];  const void* bv = d_in[6];
  const void* wo = d_in[7];  const void* bo = d_in[8];
  const void* w1 = d_in[9];  const void* b1 = d_in[10];
  const void* w2 = d_in[11]; const void* b2 = d_in[12];
  const void* g1 = d_in[13]; const void* be1 = d_in[14];
  const void* g2 = d_in[15]; const void* be2 = d_in[16];
  float* outp = (float*)d_out;   // reference output dtype: float32

  // --- workspace (peak 38 MB) ---
  const size_t MB = 1048576;
  char* ws = (char*)d_ws;
  int*    flag  = (int*)(ws + 0);
  int*    zeroc = (int*)(ws + 64);
  float*  wtab  = (float*)(ws + 256);
  float*  qb    = (float*)(ws + 1 * MB);    // [16][2048][64] f32   8MB (1..9)
  float*  kb    = (float*)(ws + 9 * MB);    // [16][2048][64] f32   8MB (9..17)
  ushort* vb    = (ushort*)(ws + 17 * MB);  // [16][2048][64] bf16  4MB (17..21)
  float*  mrow  = (float*)(ws + 21 * MB);   // [32768] f32       128KB
  ushort* ctxb  = (ushort*)(ws + 22 * MB);  // [8192][1024] bf16  16MB (22..38)
  // phase 2 reuse:
  ushort* y1    = (ushort*)(ws + 1 * MB);   // [8192][1024] bf16  16MB (1..17)
  ushort* hbuf  = (ushort*)(ws + 22 * MB);  // over dead ctx
  ushort* ffc   = (ushort*)(ws + 1 * MB);   // [2048][4096] bf16  16MB (over dead y1)

  detect_k<<<dim3(1), dim3(64), 0, stream>>>(x, flag);
  wtab_k<<<dim3(1), dim3(64), 0, stream>>>(wtab, zeroc);

  // per-batch: QKV projections + attention -> ctx (bf16)
  for (int b = 0; b < 4; ++b) {
    sgemm<0><<<dim3(16, 32), 256, 0, stream>>>(x, flag, b * 2048, wq, bq, flag,
                                               nullptr, nullptr, nullptr, qb, wtab,
                                               1024, 1024, b * 2048);
    sgemm<1><<<dim3(16, 32), 256, 0, stream>>>(x, flag, b * 2048, wk, bk, flag,
                                               nullptr, nullptr, nullptr, kb, wtab,
                                               1024, 1024, b * 2048);
    sgemm<2><<<dim3(16, 32), 256, 0, stream>>>(x, flag, b * 2048, wv, bv, flag,
                                               nullptr, nullptr, vb, nullptr, wtab,
                                               1024, 1024, b * 2048);
    attn_max_k<<<dim3(8, 16), 256, 0, stream>>>(qb, kb, mrow);
    attn_acc_k<<<dim3(8, 16), 256, 0, stream>>>(qb, kb, vb, mrow, ctxb, b);
  }

  // O-proj + residual(x) -> y1 (bf16) ; LN1 -> h (bf16)
  sgemm<4><<<dim3(16, 128), 256, 0, stream>>>(ctxb, zeroc, 0, wo, bo, flag,
                                              x, flag, y1, nullptr, wtab,
                                              1024, 1024, 0);
  ln_k<<<dim3(8192), 256, 0, stream>>>(y1, g1, be1, flag, hbuf);

  // FFN in 4 M-chunks: FF1(relu) -> ffc (bf16) ; FF2 + residual(h) -> d_out fp32
  for (int c = 0; c < 4; ++c) {
    sgemm<3><<<dim3(64, 32), 256, 0, stream>>>(hbuf, zeroc, c * 2048, w1, b1, flag,
                                               nullptr, nullptr, ffc, nullptr, wtab,
                                               4096, 1024, 0);
    sgemm<5><<<dim3(16, 32), 256, 0, stream>>>(ffc, zeroc, 0, w2, b2, flag,
                                               hbuf, zeroc, nullptr, outp, wtab,
                                               1024, 4096, c * 2048);
  }
  // LN2 in-place on d_out (fp32 in/out)
  ln_f32_k<<<dim3(8192), 256, 0, stream>>>(outp, g2, be2, flag);
}